// Round 16
// baseline (603.382 us; speedup 1.0000x reference)
//
#include <hip/hip_runtime.h>
#include <hip/hip_bf16.h>
#include <math.h>

// Problem constants
#define B_ 8
#define Q_ 64
#define S_ 48
#define T_ 128
#define H_ 768
#define NH_ 12
#define HD_ 64
#define FF_ 3072

typedef float f32x4 __attribute__((ext_vector_type(4)));
typedef short s16x8 __attribute__((ext_vector_type(8)));
typedef short s16x4 __attribute__((ext_vector_type(4)));

__device__ __forceinline__ float ldT(const float* p, size_t i) { return p[i]; }
__device__ __forceinline__ float ldT(const __hip_bfloat16* p, size_t i) { return __bfloat162float(p[i]); }
__device__ __forceinline__ void stT(float* p, size_t i, float v) { p[i] = v; }
__device__ __forceinline__ void stT(__hip_bfloat16* p, size_t i, float v) { p[i] = __float2bfloat16(v); }

__device__ __forceinline__ short f2bf(float f) {
  __hip_bfloat16 h = __float2bfloat16(f);
  return *reinterpret_cast<short*>(&h);
}

// gelu via sigmoid form of tanh-approx (R10-proven, absmax unchanged)
__device__ __forceinline__ float gelu_f(float x) {
  float z = 1.5957691216f * (x + 0.044715f * x * x * x);
  z = fminf(z, 80.0f);
  float e = __expf(z);
  return x * e / (e + 1.0f);
}

// async global->LDS, 16B per lane
__device__ __forceinline__ void gld_lds16(const void* g, void* l) {
  __builtin_amdgcn_global_load_lds(
      (const __attribute__((address_space(1))) void*)g,
      (__attribute__((address_space(3))) void*)l, 16, 0, 0);
}

__device__ __forceinline__ int swz_off(int row, int kc) {
  // byte offset of 16B chunk (row, k-chunk kc) in a [rows][32] bf16 tile,
  // slot swizzled: slot = kc ^ ((row>>1)&3)  (involution)
  return row * 64 + ((kc ^ ((row >> 1) & 3)) << 4);
}

#define WAITV4() asm volatile("s_waitcnt vmcnt(4)" ::: "memory")
#define WAITV5() asm volatile("s_waitcnt vmcnt(5)" ::: "memory")
#define WAITV0() asm volatile("s_waitcnt vmcnt(0)" ::: "memory")
#define BARX()   do { __builtin_amdgcn_s_barrier(); asm volatile("" ::: "memory"); } while (0)

// ---------------------------------------------------------------------------
// MFMA bf16 GEMM (R11-best + optional split-K): C = act(A @ BT^T + b)
// 128x128 tile, BK=32, 256 thr (4 waves 2x2), per-wave 64x64.
// 3-deep LDS ring, counted vmcnt(4), one barrier/K-step, unroll-by-3.
// SPLIT==2: grid doubles; high half computes K-half 1 into C2 (no bias);
// reduce is fused into the following LN kernel.
// ---------------------------------------------------------------------------
template<int KK, int SPLIT, typename OT, bool BIAS, bool GELU>
__global__ __launch_bounds__(256) void gemm_mfma(
    const __hip_bfloat16* __restrict__ A,   // [M,KK]
    const __hip_bfloat16* __restrict__ BT,  // [N,KK]
    const float* __restrict__ bias, OT* __restrict__ C, OT* __restrict__ C2,
    int N, int nbx, int GB)
{
  constexpr int KH = KK / SPLIT;
  constexpr int NT = KH / 32;
  static_assert(NT % 3 == 0 && NT >= 6, "KH must be multiple of 96");
  __shared__ char sm[3][16384];   // per buf: A 8KB @0, B 8KB @8192

  int bid = blockIdx.x, spl = 0;
  if (SPLIT == 2) {
    const int hf = gridDim.x >> 1;
    if (bid >= hf) { spl = 1; bid -= hf; }
  }
  const int cpx = (SPLIT == 2 ? (gridDim.x >> 1) : gridDim.x) >> 3;
  const int xcd = bid & 7;
  const int ci  = bid >> 3;
  const int gsz = GB * nbx;
  const int g   = ci / gsz;
  const int r2  = ci - g * gsz;
  const int bn  = r2 / GB;
  const int bi  = r2 - bn * GB;
  const int bm  = xcd * (cpx / nbx) + g * GB + bi;
  const int m0 = bm * 128, n0 = bn * 128;
  const int k00 = spl * KH;
  OT* Cw = spl ? C2 : C;

  const int tid = threadIdx.x;
  const int lane = tid & 63;
  const int wid = tid >> 6;
  const int wr = wid >> 1, wc = wid & 1;
  const int kcg = lane >> 4, rl = lane & 15;

  const __hip_bfloat16* pA[2];
  const __hip_bfloat16* pB[2];
  #pragma unroll
  for (int r = 0; r < 2; ++r) {
    const int c = tid + r * 256, row = c >> 2, slot = c & 3;
    const int kc = slot ^ ((row >> 1) & 3);
    pA[r] = A + (size_t)(m0 + row) * KK + k00 + kc * 8;
    pB[r] = BT + (size_t)(n0 + row) * KK + k00 + kc * 8;
  }
  auto stageT = [&](char* base, int off) {
    gld_lds16(pA[0] + off, base + tid * 16);
    gld_lds16(pA[1] + off, base + tid * 16 + 4096);
    gld_lds16(pB[0] + off, base + 8192 + tid * 16);
    gld_lds16(pB[1] + off, base + 8192 + tid * 16 + 4096);
  };

  int woffA[4], woffB[4];
  #pragma unroll
  for (int m = 0; m < 4; ++m)
    woffA[m] = swz_off(wr * 64 + m * 16 + rl, kcg);
  #pragma unroll
  for (int n = 0; n < 4; ++n)
    woffB[n] = 8192 + swz_off(wc * 64 + n * 16 + rl, kcg);

  f32x4 acc[4][4] = {};
  s16x8 af[4], bf[4];
  auto reads = [&](const char* base) {
    #pragma unroll
    for (int m = 0; m < 4; ++m) af[m] = *(const s16x8*)(base + woffA[m]);
    #pragma unroll
    for (int n = 0; n < 4; ++n) bf[n] = *(const s16x8*)(base + woffB[n]);
  };
  auto mfmas = [&]() {
    #pragma unroll
    for (int m = 0; m < 4; ++m)
      #pragma unroll
      for (int n = 0; n < 4; ++n)
        acc[m][n] = __builtin_amdgcn_mfma_f32_16x16x32_bf16(af[m], bf[n], acc[m][n], 0, 0, 0);
  };

  stageT(sm[0], 0);
  stageT(sm[1], 32);
  #pragma unroll
  for (int r = 0; r < 2; ++r) { pA[r] += 64; pB[r] += 64; }

  #pragma unroll 1
  for (int it = 0; it < NT / 3 - 1; ++it) {
    WAITV4(); BARX(); reads(sm[0]); stageT(sm[2], 0);  mfmas();
    WAITV4(); BARX(); reads(sm[1]); stageT(sm[0], 32); mfmas();
    WAITV4(); BARX(); reads(sm[2]); stageT(sm[1], 64); mfmas();
    #pragma unroll
    for (int r = 0; r < 2; ++r) { pA[r] += 96; pB[r] += 96; }
  }
  WAITV4(); BARX(); reads(sm[0]); stageT(sm[2], 0); mfmas();
  WAITV4(); BARX(); reads(sm[1]); mfmas();
  WAITV0(); BARX(); reads(sm[2]); mfmas();

  const int colb = n0 + wc * 64 + rl;
  const int rowb = m0 + wr * 64 + (lane >> 4) * 4;
  float bv[4];
  #pragma unroll
  for (int n = 0; n < 4; ++n)
    bv[n] = (BIAS && spl == 0) ? bias[colb + n * 16] : 0.0f;
  #pragma unroll
  for (int m = 0; m < 4; ++m) {
    #pragma unroll
    for (int r = 0; r < 4; ++r) {
      const int row = rowb + m * 16 + r;
      #pragma unroll
      for (int n = 0; n < 4; ++n) {
        float v = acc[m][n][r] + bv[n];
        if (GELU) v = gelu_f(v);
        stT(Cw, (size_t)row * N + colb + n * 16, v);
      }
    }
  }
}

// ---------------------------------------------------------------------------
// Fat-wave variant (R11-best + optional split-K): tile 128x192, per-wave
// 64x96, acc[4][6]. 3-ring 60KB -> 2 blocks/CU, vmcnt(5), unroll-by-3.
// ---------------------------------------------------------------------------
template<int KK, int SPLIT, typename OT, bool BIAS, bool GELU>
__global__ __launch_bounds__(256, 2) void gemm_fat(
    const __hip_bfloat16* __restrict__ A,   // [M,KK]
    const __hip_bfloat16* __restrict__ BT,  // [N,KK]
    const float* __restrict__ bias, OT* __restrict__ C, OT* __restrict__ C2,
    int N, int nbx, int GB)
{
  constexpr int KH = KK / SPLIT;
  constexpr int NT = KH / 32;
  static_assert(NT % 3 == 0 && NT >= 6, "KH must be multiple of 96");
  __shared__ char sm[3][20480];   // per buf: A 8KB @0, B 12KB @8192

  int bid = blockIdx.x, spl = 0;
  if (SPLIT == 2) {
    const int hf = gridDim.x >> 1;
    if (bid >= hf) { spl = 1; bid -= hf; }
  }
  const int cpx = (SPLIT == 2 ? (gridDim.x >> 1) : gridDim.x) >> 3;
  const int xcd = bid & 7;
  const int ci  = bid >> 3;
  const int gsz = GB * nbx;
  const int g   = ci / gsz;
  const int r2  = ci - g * gsz;
  const int bn  = r2 / GB;
  const int bi  = r2 - bn * GB;
  const int bm  = xcd * (cpx / nbx) + g * GB + bi;
  const int m0 = bm * 128, n0 = bn * 192;
  const int k00 = spl * KH;
  OT* Cw = spl ? C2 : C;

  const int tid = threadIdx.x;
  const int lane = tid & 63;
  const int wid = tid >> 6;
  const int wm = wid >> 1;
  const int wn = wid & 1;
  const int kcg = lane >> 4, rl = lane & 15;

  const __hip_bfloat16* pA[2];
  const __hip_bfloat16* pB[3];
  #pragma unroll
  for (int r = 0; r < 2; ++r) {
    const int c = tid + r * 256, row = c >> 2, slot = c & 3;
    const int kc = slot ^ ((row >> 1) & 3);
    pA[r] = A + (size_t)(m0 + row) * KK + k00 + kc * 8;
  }
  #pragma unroll
  for (int r = 0; r < 3; ++r) {
    const int c = tid + r * 256, row = c >> 2, slot = c & 3;
    const int kc = slot ^ ((row >> 1) & 3);
    pB[r] = BT + (size_t)(n0 + row) * KK + k00 + kc * 8;
  }
  auto stageT = [&](char* base, int off) {
    gld_lds16(pA[0] + off, base + tid * 16);
    gld_lds16(pA[1] + off, base + tid * 16 + 4096);
    gld_lds16(pB[0] + off, base + 8192 + tid * 16);
    gld_lds16(pB[1] + off, base + 8192 + tid * 16 + 4096);
    gld_lds16(pB[2] + off, base + 8192 + tid * 16 + 8192);
  };

  int woffA[4], woffB[6];
  #pragma unroll
  for (int m = 0; m < 4; ++m)
    woffA[m] = swz_off(wm * 64 + m * 16 + rl, kcg);
  #pragma unroll
  for (int n = 0; n < 6; ++n)
    woffB[n] = 8192 + swz_off(wn * 96 + n * 16 + rl, kcg);

  f32x4 acc[4][6] = {};
  s16x8 af[4], bf[6];
  auto reads = [&](const char* base) {
    #pragma unroll
    for (int m = 0; m < 4; ++m) af[m] = *(const s16x8*)(base + woffA[m]);
    #pragma unroll
    for (int n = 0; n < 6; ++n) bf[n] = *(const s16x8*)(base + woffB[n]);
  };
  auto mfmas = [&]() {
    #pragma unroll
    for (int m = 0; m < 4; ++m)
      #pragma unroll
      for (int n = 0; n < 6; ++n)
        acc[m][n] = __builtin_amdgcn_mfma_f32_16x16x32_bf16(af[m], bf[n], acc[m][n], 0, 0, 0);
  };

  stageT(sm[0], 0);
  stageT(sm[1], 32);
  #pragma unroll
  for (int r = 0; r < 2; ++r) pA[r] += 64;
  #pragma unroll
  for (int r = 0; r < 3; ++r) pB[r] += 64;

  #pragma unroll 1
  for (int it = 0; it < NT / 3 - 1; ++it) {
    WAITV5(); BARX(); reads(sm[0]); stageT(sm[2], 0);  mfmas();
    WAITV5(); BARX(); reads(sm[1]); stageT(sm[0], 32); mfmas();
    WAITV5(); BARX(); reads(sm[2]); stageT(sm[1], 64); mfmas();
    #pragma unroll
    for (int r = 0; r < 2; ++r) pA[r] += 96;
    #pragma unroll
    for (int r = 0; r < 3; ++r) pB[r] += 96;
  }
  WAITV5(); BARX(); reads(sm[0]); stageT(sm[2], 0); mfmas();
  WAITV5(); BARX(); reads(sm[1]); mfmas();
  WAITV0(); BARX(); reads(sm[2]); mfmas();

  const int colb = n0 + wn * 96 + rl;
  const int rowb = m0 + wm * 64 + (lane >> 4) * 4;
  float bv[6];
  #pragma unroll
  for (int n = 0; n < 6; ++n)
    bv[n] = (BIAS && spl == 0) ? bias[colb + n * 16] : 0.0f;
  #pragma unroll
  for (int m = 0; m < 4; ++m) {
    #pragma unroll
    for (int r = 0; r < 4; ++r) {
      const int row = rowb + m * 16 + r;
      #pragma unroll
      for (int n = 0; n < 6; ++n) {
        float v = acc[m][n][r] + bv[n];
        if (GELU) v = gelu_f(v);
        stT(Cw, (size_t)row * N + colb + n * 16, v);
      }
    }
  }
}

// ---------------------------------------------------------------------------
// fp32 LDS-tiled GEMM (q-projection only), templated output
// ---------------------------------------------------------------------------
template<typename OT>
__global__ __launch_bounds__(256) void gemm64(
    const float* __restrict__ A, const float* __restrict__ W,
    OT* __restrict__ C, int M, int N, int K)
{
  __shared__ float As[16][65];
  __shared__ float Ws[16][65];
  const int tid = threadIdx.x;
  const int m0 = blockIdx.y * 64;
  const int n0 = blockIdx.x * 64;
  const int tx = (tid & 15) * 4;
  const int ty = (tid >> 4) * 4;
  float acc[4][4] = {};

  for (int k0 = 0; k0 < K; k0 += 16) {
    #pragma unroll
    for (int r = 0; r < 4; ++r) {
      int idx = tid + r * 256;
      int mm = idx >> 4, kk = idx & 15;
      As[kk][mm] = A[(size_t)(m0 + mm) * K + (k0 + kk)];
    }
    #pragma unroll
    for (int r = 0; r < 4; ++r) {
      int idx = tid + r * 256;
      int kk = idx >> 6, nn = idx & 63;
      Ws[kk][nn] = W[(size_t)(k0 + kk) * N + (n0 + nn)];
    }
    __syncthreads();
    #pragma unroll
    for (int kk = 0; kk < 16; ++kk) {
      float a[4], b[4];
      #pragma unroll
      for (int i = 0; i < 4; ++i) a[i] = As[kk][ty + i];
      #pragma unroll
      for (int j = 0; j < 4; ++j) b[j] = Ws[kk][tx + j];
      #pragma unroll
      for (int i = 0; i < 4; ++i)
        #pragma unroll
        for (int j = 0; j < 4; ++j) acc[i][j] += a[i] * b[j];
    }
    __syncthreads();
  }
  #pragma unroll
  for (int i = 0; i < 4; ++i)
    #pragma unroll
    for (int j = 0; j < 4; ++j)
      stT(C, (size_t)(m0 + ty + i) * N + (n0 + tx + j), acc[i][j]);
}

// ---------------------------------------------------------------------------
// Merged weight transpose-cast: all 4 weights in ONE dispatch. (R15-proven)
// ---------------------------------------------------------------------------
__device__ __forceinline__ void tcast_body(
    const float* W, __hip_bfloat16* WT, int K, int N, int bx, int by, int tid,
    float (*t)[33])
{
  const int n0 = bx * 32, k0 = by * 32;
  const int x = tid & 31, y4 = (tid >> 5) * 4;
  #pragma unroll
  for (int i = 0; i < 4; ++i)
    t[y4 + i][x] = W[(size_t)(k0 + y4 + i) * N + n0 + x];
  __syncthreads();
  #pragma unroll
  for (int i = 0; i < 4; ++i)
    WT[(size_t)(n0 + y4 + i) * K + k0 + x] = __float2bfloat16(t[x][y4 + i]);
}

__global__ __launch_bounds__(256) void wtrans_all(
    const float* __restrict__ Wkv, __hip_bfloat16* __restrict__ WkvT,
    const float* __restrict__ Wo, __hip_bfloat16* __restrict__ WoT,
    const float* __restrict__ W1, __hip_bfloat16* __restrict__ W1T,
    const float* __restrict__ W2, __hip_bfloat16* __restrict__ W2T)
{
  __shared__ float t[32][33];
  const int bid = blockIdx.x;
  const int tid = threadIdx.x;
  if (bid < 576) {
    tcast_body(Wkv, WkvT, H_, H_, bid % 24, bid / 24, tid, t);
  } else if (bid < 1152) {
    const int s = bid - 576;
    tcast_body(Wo, WoT, H_, H_, s % 24, s / 24, tid, t);
  } else if (bid < 3456) {
    const int s = bid - 1152;
    tcast_body(W1, W1T, H_, FF_, s % 96, s / 96, tid, t);
  } else {
    const int s = bid - 3456;
    tcast_body(W2, W2T, FF_, H_, s % 24, s / 24, tid, t);
  }
}

// elementwise cast f32 -> bf16, 4 elems/thread (dedicated, zero-LDS)
__global__ __launch_bounds__(256) void cast_f32_bf16(
    const float* __restrict__ x, __hip_bfloat16* __restrict__ y, size_t n4)
{
  const size_t i = (size_t)blockIdx.x * 256 + threadIdx.x;
  if (i >= n4) return;
  const float4 v = ((const float4*)x)[i];
  __hip_bfloat16 o[4] = { __float2bfloat16(v.x), __float2bfloat16(v.y),
                          __float2bfloat16(v.z), __float2bfloat16(v.w) };
  *(ushort4*)(y + i * 4) = *(ushort4*)o;
}

// ---------------------------------------------------------------------------
// MFMA attention. Block = (s, h, b). 256 threads = 4 waves (2x2).  (R4, unchanged)
// ---------------------------------------------------------------------------
__global__ __launch_bounds__(256) void attn_mfma(
    const __hip_bfloat16* __restrict__ qp,   // [B*Q][H] bf16
    const __hip_bfloat16* __restrict__ kvp,  // [B*S*T][H] bf16
    const int* __restrict__ mask,
    __hip_bfloat16* __restrict__ res)        // [B,Q,S,H] bf16
{
  const int s = blockIdx.x, h = blockIdx.y, b = blockIdx.z;
  __shared__ __align__(16) char lds[66048];
  char* Ks = lds;
  char* VT = lds + 16384;
  char* SC = lds + 32768;
  float* mv = (float*)(lds + 65536);

  const int tid = threadIdx.x;
  const int lane = tid & 63;
  const int wid = tid >> 6;
  const int wr = wid >> 1, wc = wid & 1;
  const int kcg = lane >> 4, rl = lane & 15;

  if (tid < 128) mv[tid] = (float)mask[((size_t)b * S_ + s) * T_ + tid] * -10000.0f;

  {
    const __hip_bfloat16* qb = qp + ((size_t)b * Q_) * H_ + h * HD_;
    #pragma unroll
    for (int r = 0; r < 2; ++r) {
      const int c = tid + r * 256;
      const int qq = c >> 3, sc = c & 7;
      const int kc8 = sc ^ (qq & 7);
      gld_lds16(qb + (size_t)qq * H_ + kc8 * 8, SC + c * 16);
    }
  }
  {
    const int kc8 = tid & 7, tg = tid >> 3;
    const int t0 = tg * 4;
    const __hip_bfloat16* kb = kvp + (((size_t)b * S_ + s) * T_) * H_ + h * HD_ + kc8 * 8;
    s16x8 r0 = *(const s16x8*)(kb + (size_t)(t0 + 0) * H_);
    s16x8 r1 = *(const s16x8*)(kb + (size_t)(t0 + 1) * H_);
    s16x8 r2 = *(const s16x8*)(kb + (size_t)(t0 + 2) * H_);
    s16x8 r3 = *(const s16x8*)(kb + (size_t)(t0 + 3) * H_);
    *(s16x8*)(Ks + (t0 + 0) * 128 + ((kc8 ^ ((t0 + 0) & 7)) << 4)) = r0;
    *(s16x8*)(Ks + (t0 + 1) * 128 + ((kc8 ^ ((t0 + 1) & 7)) << 4)) = r1;
    *(s16x8*)(Ks + (t0 + 2) * 128 + ((kc8 ^ ((t0 + 2) & 7)) << 4)) = r2;
    *(s16x8*)(Ks + (t0 + 3) * 128 + ((kc8 ^ ((t0 + 3) & 7)) << 4)) = r3;
    const int tc = tg >> 1;
    const int toff = (tg & 1) * 8;
    #pragma unroll
    for (int j = 0; j < 8; ++j) {
      s16x4 v4 = { r0[j], r1[j], r2[j], r3[j] };
      const int d = kc8 * 8 + j;
      *(s16x4*)(VT + d * 256 + ((tc ^ (d & 15)) << 4) + toff) = v4;
    }
  }
  __syncthreads();

  f32x4 acc[2][4] = {};
  {
    s16x8 af[2][2], bf[2][4];
    #pragma unroll
    for (int kk = 0; kk < 2; ++kk) {
      #pragma unroll
      for (int m = 0; m < 2; ++m) {
        const int q = wr * 32 + m * 16 + rl;
        const int kc8 = kk * 4 + kcg;
        af[kk][m] = *(const s16x8*)(SC + q * 128 + ((kc8 ^ (q & 7)) << 4));
      }
      #pragma unroll
      for (int n = 0; n < 4; ++n) {
        const int t = wc * 64 + n * 16 + rl;
        const int kc8 = kk * 4 + kcg;
        bf[kk][n] = *(const s16x8*)(Ks + t * 128 + ((kc8 ^ (t & 7)) << 4));
      }
    }
    #pragma unroll
    for (int kk = 0; kk < 2; ++kk)
      #pragma unroll
      for (int m = 0; m < 2; ++m)
        #pragma unroll
        for (int n = 0; n < 4; ++n)
          acc[m][n] = __builtin_amdgcn_mfma_f32_16x16x32_bf16(af[kk][m], bf[kk][n], acc[m][n], 0, 0, 0);
  }
  __syncthreads();

  #pragma unroll
  for (int m = 0; m < 2; ++m)
    #pragma unroll
    for (int n = 0; n < 4; ++n)
      #pragma unroll
      for (int r = 0; r < 4; ++r) {
        const int q = wr * 32 + m * 16 + (lane >> 4) * 4 + r;
        const int t = wc * 64 + n * 16 + rl;
        const int tc32 = t >> 2;
        *(float*)(SC + q * 512 + ((tc32 ^ (q & 31)) << 4) + (t & 3) * 4) =
            acc[m][n][r] * 0.125f + mv[t];
      }
  __syncthreads();

  {
    const int q = tid >> 2, quarter = tid & 3;
    float vals[32];
    #pragma unroll
    for (int j = 0; j < 8; ++j) {
      const int tc32 = quarter * 8 + j;
      const f32x4 c = *(const f32x4*)(SC + q * 512 + ((tc32 ^ (q & 31)) << 4));
      vals[j * 4 + 0] = c[0]; vals[j * 4 + 1] = c[1];
      vals[j * 4 + 2] = c[2]; vals[j * 4 + 3] = c[3];
    }
    float mx = -1e30f;
    #pragma unroll
    for (int i = 0; i < 32; ++i) mx = fmaxf(mx, vals[i]);
    mx = fmaxf(mx, __shfl_xor(mx, 1, 64));
    mx = fmaxf(mx, __shfl_xor(mx, 2, 64));
    float sum = 0.0f;
    #pragma unroll
    for (int i = 0; i < 32; ++i) { vals[i] = expf(vals[i] - mx); sum += vals[i]; }
    sum += __shfl_xor(sum, 1, 64);
    sum += __shfl_xor(sum, 2, 64);
    const float inv = 1.0f / sum;
    #pragma unroll
    for (int jj = 0; jj < 4; ++jj) {
      const int tcp = quarter * 4 + jj;
      s16x8 pk;
      #pragma unroll
      for (int i = 0; i < 8; ++i) pk[i] = f2bf(vals[jj * 8 + i] * inv);
      *(s16x8*)(SC + q * 512 + ((tcp ^ (q & 15)) << 4)) = pk;
    }
  }
  __syncthreads();

  f32x4 oacc[2][2] = {};
  #pragma unroll
  for (int kt = 0; kt < 4; ++kt) {
    s16x8 pa[2], vb[2];
    #pragma unroll
    for (int m = 0; m < 2; ++m) {
      const int q = wr * 32 + m * 16 + rl;
      const int tcp = kt * 4 + kcg;
      pa[m] = *(const s16x8*)(SC + q * 512 + ((tcp ^ (q & 15)) << 4));
    }
    #pragma unroll
    for (int n = 0; n < 2; ++n) {
      const int d = wc * 32 + n * 16 + rl;
      const int tc = kt * 4 + kcg;
      vb[n] = *(const s16x8*)(VT + d * 256 + ((tc ^ (d & 15)) << 4));
    }
    #pragma unroll
    for (int m = 0; m < 2; ++m)
      #pragma unroll
      for (int n = 0; n < 2; ++n)
        oacc[m][n] = __builtin_amdgcn_mfma_f32_16x16x32_bf16(pa[m], vb[n], oacc[m][n], 0, 0, 0);
  }
  #pragma unroll
  for (int m = 0; m < 2; ++m)
    #pragma unroll
    for (int n = 0; n < 2; ++n)
      #pragma unroll
      for (int r = 0; r < 4; ++r) {
        const int q = wr * 32 + m * 16 + (lane >> 4) * 4 + r;
        const int d = wc * 32 + n * 16 + rl;
        res[(((size_t)b * Q_ + q) * S_ + s) * H_ + h * HD_ + d] =
            __float2bfloat16(oacc[m][n][r]);
      }
}

// ---------------------------------------------------------------------------
// Row LayerNorm over H=768 with NADD extra inputs summed in (0, 1, or 2).
// ---------------------------------------------------------------------------
template<int NADD, typename IT, typename OT>
__global__ __launch_bounds__(256) void ln_kernel(
    const IT* __restrict__ X, const IT* __restrict__ X2,
    const IT* __restrict__ X3,
    const float* __restrict__ g, const float* __restrict__ bta,
    OT* __restrict__ Y)
{
  const size_t row = blockIdx.x;
  const int tid = threadIdx.x;
  float v[3];
  #pragma unroll
  for (int i = 0; i < 3; ++i) {
    int c = tid + i * 256;
    v[i] = ldT(X, row * H_ + c);
    if (NADD >= 1) v[i] += ldT(X2, row * H_ + c);
    if (NADD >= 2) v[i] += ldT(X3, row * H_ + c);
  }
  float sum = v[0] + v[1] + v[2];
  #pragma unroll
  for (int off = 32; off > 0; off >>= 1) sum += __shfl_down(sum, off, 64);
  __shared__ float red[8];
  const int w = tid >> 6;
  if ((tid & 63) == 0) red[w] = sum;
  __syncthreads();
  const float mean = (red[0] + red[1] + red[2] + red[3]) * (1.0f / 768.0f);
  float vs = 0.0f;
  #pragma unroll
  for (int i = 0; i < 3; ++i) { v[i] -= mean; vs += v[i] * v[i]; }
  #pragma unroll
  for (int off = 32; off > 0; off >>= 1) vs += __shfl_down(vs, off, 64);
  if ((tid & 63) == 0) red[4 + w] = vs;
  __syncthreads();
  const float rstd = rsqrtf((red[4] + red[5] + red[6] + red[7]) * (1.0f / 768.0f) + 1e-12f);
  #pragma unroll
  for (int i = 0; i < 3; ++i) {
    int c = tid + i * 256;
    stT(Y, row * H_ + c, v[i] * rstd * g[c] + bta[c]);
  }
}

// ---------------------------------------------------------------------------
extern "C" void kernel_launch(void* const* d_in, const int* in_sizes, int n_in,
                              void* d_out, int out_size, void* d_ws, size_t ws_size,
                              hipStream_t stream) {
  const float* q    = (const float*)d_in[0];
  const float* k    = (const float*)d_in[1];
  const int*   mask = (const int*)d_in[2];
  const float* Wq   = (const float*)d_in[3];
  const float* Wkv  = (const float*)d_in[4];
  const float* Wo   = (const float*)d_in[5];
  const float* bo   = (const float*)d_in[6];
  const float* ln1g = (const float*)d_in[7];
  const float* ln1b = (const float*)d_in[8];
  const float* W1   = (const float*)d_in[9];
  const float* b1   = (const float*)d_in[10];
  const float* W2   = (const float*)d_in[11];
  const float* b2   = (const float*)d_in[12];
  const float* ln2g = (const float*)d_in[13];
  const float* ln2b = (const float*)d_in[14];
  float* out = (float*)d_out;

  const int MROWS = B_ * Q_ * S_;           // 24576
  const int KVROWS = B_ * S_ * T_;          // 49152

  // workspace layout (bytes), lifetime-based reuse:
  char* ws = (char*)d_ws;
  __hip_bfloat16* kbf   = (__hip_bfloat16*)ws;                       // 75.5MB [dead after kv gemm]
  __hip_bfloat16* aprea = (__hip_bfloat16*)ws;                       // 37.7MB (reuses kbf)
  __hip_bfloat16* apreb = (__hip_bfloat16*)(ws + 37748736);          // 37.7MB [both dead after LN1]
  __hip_bfloat16* kvp   = (__hip_bfloat16*)(ws + 75497472);          // 75.5MB [dead after attn]
  __hip_bfloat16* ffn1  = (__hip_bfloat16*)ws;                       // 151MB (reuses apre+kvp)
  __hip_bfloat16* ares  = (__hip_bfloat16*)(ws + 150994944);         // 37.7MB [dead after Wo gemm]
  __hip_bfloat16* ffn2a = ares;                                      // reuse (after ares dead)
  __hip_bfloat16* aln   = (__hip_bfloat16*)(ws + 188743680);         // 37.7MB
  __hip_bfloat16* qp    = (__hip_bfloat16*)(ws + 226492416);         // 0.8MB (bf16)
  __hip_bfloat16* WkvT  = (__hip_bfloat16*)(ws + 228065280);
  __hip_bfloat16* WoT   = (__hip_bfloat16*)(ws + 229244928);
  __hip_bfloat16* W1T   = (__hip_bfloat16*)(ws + 230424576);
  __hip_bfloat16* W2T   = (__hip_bfloat16*)(ws + 235143168);
  __hip_bfloat16* ffn2b = (__hip_bfloat16*)(ws + 239861760);         // 37.7MB

  dim3 blk(256);

  // weight prep: big cast, merged transposes, q-proj
  cast_f32_bf16<<<dim3((KVROWS * H_ / 4 + 255) / 256), blk, 0, stream>>>(
      k, kbf, (size_t)KVROWS * H_ / 4);
  wtrans_all<<<dim3(5760), blk, 0, stream>>>(
      Wkv, WkvT, Wo, WoT, W1, W1T, W2, W2T);

  // 1. q projection (fp32 in, bf16 out)
  gemm64<__hip_bfloat16><<<dim3(H_ / 64, 512 / 64), blk, 0, stream>>>(
      q, Wq, qp, 512, H_, H_);
  // 2. kv projection -> bf16   grid 2304, cpx=288, GB=6 (3 full rounds)
  gemm_mfma<768, 1, __hip_bfloat16, false, false>
      <<<dim3((KVROWS / 128) * (H_ / 128)), blk, 0, stream>>>(
      kbf, WkvT, nullptr, kvp, nullptr, H_, H_ / 128, 6);
  // 3. MFMA attention -> ares (bf16)
  attn_mfma<<<dim3(S_, NH_, B_), blk, 0, stream>>>(qp, kvp, mask, ares);
  // 4. Wo SPLIT-K2: grid 2x1152=2304 (3 full rounds at 3/CU); reduce in LN1
  gemm_mfma<768, 2, __hip_bfloat16, true, false>
      <<<dim3(2 * (MROWS / 128) * (H_ / 128)), blk, 0, stream>>>(
      ares, WoT, bo, aprea, apreb, H_, H_ / 128, 6);
  // 5. LN1 (sums the two Wo partials): aprea + apreb -> aln (bf16)
  ln_kernel<1, __hip_bfloat16, __hip_bfloat16><<<MROWS, blk, 0, stream>>>(
      aprea, apreb, nullptr, ln1g, ln1b, aln);
  // 6. aln @ W1 + b1, gelu -> ffn1 (bf16)  [FAT 128x192]  grid 3072 (6 rounds)
  gemm_fat<768, 1, __hip_bfloat16, true, true>
      <<<dim3((MROWS / 128) * (FF_ / 192)), blk, 0, stream>>>(
      aln, W1T, b1, ffn1, nullptr, FF_, FF_ / 192, 6);
  // 7. W2 SPLIT-K2 [FAT]: grid 2x768=1536 (3 full rounds at 2/CU); reduce in LN2
  gemm_fat<3072, 2, __hip_bfloat16, true, false>
      <<<dim3(2 * (MROWS / 128) * (H_ / 192)), blk, 0, stream>>>(
      ffn1, W2T, b2, ffn2a, ffn2b, H_, H_ / 192, 6);
  // 8. LN2: out = LN(aln + ffn2a + ffn2b)
  ln_kernel<2, __hip_bfloat16, float><<<MROWS, blk, 0, stream>>>(
      aln, ffn2a, ffn2b, ln2g, ln2b, out);
}

// Round 17
// 565.892 us; speedup vs baseline: 1.0662x; 1.0662x over previous
//
#include <hip/hip_runtime.h>
#include <hip/hip_bf16.h>
#include <math.h>

// Problem constants
#define B_ 8
#define Q_ 64
#define S_ 48
#define T_ 128
#define H_ 768
#define NH_ 12
#define HD_ 64
#define FF_ 3072

typedef float f32x4 __attribute__((ext_vector_type(4)));
typedef short s16x8 __attribute__((ext_vector_type(8)));
typedef short s16x4 __attribute__((ext_vector_type(4)));

__device__ __forceinline__ float ldT(const float* p, size_t i) { return p[i]; }
__device__ __forceinline__ float ldT(const __hip_bfloat16* p, size_t i) { return __bfloat162float(p[i]); }
__device__ __forceinline__ void stT(float* p, size_t i, float v) { p[i] = v; }
__device__ __forceinline__ void stT(__hip_bfloat16* p, size_t i, float v) { p[i] = __float2bfloat16(v); }

__device__ __forceinline__ short f2bf(float f) {
  __hip_bfloat16 h = __float2bfloat16(f);
  return *reinterpret_cast<short*>(&h);
}

// gelu via sigmoid form of tanh-approx (R10-proven, absmax unchanged)
__device__ __forceinline__ float gelu_f(float x) {
  float z = 1.5957691216f * (x + 0.044715f * x * x * x);
  z = fminf(z, 80.0f);
  float e = __expf(z);
  return x * e / (e + 1.0f);
}

// async global->LDS, 16B per lane
__device__ __forceinline__ void gld_lds16(const void* g, void* l) {
  __builtin_amdgcn_global_load_lds(
      (const __attribute__((address_space(1))) void*)g,
      (__attribute__((address_space(3))) void*)l, 16, 0, 0);
}

__device__ __forceinline__ int swz_off(int row, int kc) {
  // byte offset of 16B chunk (row, k-chunk kc) in a [rows][32] bf16 tile,
  // slot swizzled: slot = kc ^ ((row>>1)&3)  (involution)
  return row * 64 + ((kc ^ ((row >> 1) & 3)) << 4);
}

#define WAITV4() asm volatile("s_waitcnt vmcnt(4)" ::: "memory")
#define WAITV5() asm volatile("s_waitcnt vmcnt(5)" ::: "memory")
#define WAITV0() asm volatile("s_waitcnt vmcnt(0)" ::: "memory")
#define BARX()   do { __builtin_amdgcn_s_barrier(); asm volatile("" ::: "memory"); } while (0)

// ---------------------------------------------------------------------------
// MFMA bf16 GEMM (R11-best): C = act(A[M,K] @ BT[N,K]^T + b)
// 128x128 tile, BK=32, 256 thr (4 waves 2x2), per-wave 64x64.
// 3-deep LDS ring, counted vmcnt(4), one barrier/K-step, unroll-by-3.
// ---------------------------------------------------------------------------
template<int KK, typename OT, bool BIAS, bool GELU>
__global__ __launch_bounds__(256) void gemm_mfma(
    const __hip_bfloat16* __restrict__ A,   // [M,KK]
    const __hip_bfloat16* __restrict__ BT,  // [N,KK]
    const float* __restrict__ bias, OT* __restrict__ C,
    int N, int nbx, int GB)
{
  constexpr int NT = KK / 32;
  static_assert(NT % 3 == 0 && NT >= 6, "KK must be multiple of 96");
  __shared__ char sm[3][16384];   // per buf: A 8KB @0, B 8KB @8192

  const int cpx = gridDim.x >> 3;
  const int xcd = blockIdx.x & 7;
  const int ci  = blockIdx.x >> 3;
  const int gsz = GB * nbx;
  const int g   = ci / gsz;
  const int r2  = ci - g * gsz;
  const int bn  = r2 / GB;
  const int bi  = r2 - bn * GB;
  const int bm  = xcd * (cpx / nbx) + g * GB + bi;
  const int m0 = bm * 128, n0 = bn * 128;

  const int tid = threadIdx.x;
  const int lane = tid & 63;
  const int wid = tid >> 6;
  const int wr = wid >> 1, wc = wid & 1;
  const int kcg = lane >> 4, rl = lane & 15;

  const __hip_bfloat16* pA[2];
  const __hip_bfloat16* pB[2];
  #pragma unroll
  for (int r = 0; r < 2; ++r) {
    const int c = tid + r * 256, row = c >> 2, slot = c & 3;
    const int kc = slot ^ ((row >> 1) & 3);
    pA[r] = A + (size_t)(m0 + row) * KK + kc * 8;
    pB[r] = BT + (size_t)(n0 + row) * KK + kc * 8;
  }
  auto stageT = [&](char* base, int off) {
    gld_lds16(pA[0] + off, base + tid * 16);
    gld_lds16(pA[1] + off, base + tid * 16 + 4096);
    gld_lds16(pB[0] + off, base + 8192 + tid * 16);
    gld_lds16(pB[1] + off, base + 8192 + tid * 16 + 4096);
  };

  int woffA[4], woffB[4];
  #pragma unroll
  for (int m = 0; m < 4; ++m)
    woffA[m] = swz_off(wr * 64 + m * 16 + rl, kcg);
  #pragma unroll
  for (int n = 0; n < 4; ++n)
    woffB[n] = 8192 + swz_off(wc * 64 + n * 16 + rl, kcg);

  f32x4 acc[4][4] = {};
  s16x8 af[4], bf[4];
  auto reads = [&](const char* base) {
    #pragma unroll
    for (int m = 0; m < 4; ++m) af[m] = *(const s16x8*)(base + woffA[m]);
    #pragma unroll
    for (int n = 0; n < 4; ++n) bf[n] = *(const s16x8*)(base + woffB[n]);
  };
  auto mfmas = [&]() {
    #pragma unroll
    for (int m = 0; m < 4; ++m)
      #pragma unroll
      for (int n = 0; n < 4; ++n)
        acc[m][n] = __builtin_amdgcn_mfma_f32_16x16x32_bf16(af[m], bf[n], acc[m][n], 0, 0, 0);
  };

  stageT(sm[0], 0);
  stageT(sm[1], 32);
  #pragma unroll
  for (int r = 0; r < 2; ++r) { pA[r] += 64; pB[r] += 64; }

  #pragma unroll 1
  for (int it = 0; it < NT / 3 - 1; ++it) {
    WAITV4(); BARX(); reads(sm[0]); stageT(sm[2], 0);  mfmas();
    WAITV4(); BARX(); reads(sm[1]); stageT(sm[0], 32); mfmas();
    WAITV4(); BARX(); reads(sm[2]); stageT(sm[1], 64); mfmas();
    #pragma unroll
    for (int r = 0; r < 2; ++r) { pA[r] += 96; pB[r] += 96; }
  }
  WAITV4(); BARX(); reads(sm[0]); stageT(sm[2], 0); mfmas();
  WAITV4(); BARX(); reads(sm[1]); mfmas();
  WAITV0(); BARX(); reads(sm[2]); mfmas();

  const int colb = n0 + wc * 64 + rl;
  const int rowb = m0 + wr * 64 + (lane >> 4) * 4;
  float bv[4];
  #pragma unroll
  for (int n = 0; n < 4; ++n) bv[n] = BIAS ? bias[colb + n * 16] : 0.0f;
  #pragma unroll
  for (int m = 0; m < 4; ++m) {
    #pragma unroll
    for (int r = 0; r < 4; ++r) {
      const int row = rowb + m * 16 + r;
      #pragma unroll
      for (int n = 0; n < 4; ++n) {
        float v = acc[m][n][r] + bv[n];
        if (GELU) v = gelu_f(v);
        stT(C, (size_t)row * N + colb + n * 16, v);
      }
    }
  }
}

// ---------------------------------------------------------------------------
// Fat-wave variant (R11-best): tile 128x192, per-wave 64x96, acc[4][6].
// 3-ring 60KB -> 2 blocks/CU, counted vmcnt(5), unroll-by-3.
// ---------------------------------------------------------------------------
template<int KK, typename OT, bool BIAS, bool GELU>
__global__ __launch_bounds__(256, 2) void gemm_fat(
    const __hip_bfloat16* __restrict__ A,   // [M,KK]
    const __hip_bfloat16* __restrict__ BT,  // [N,KK]
    const float* __restrict__ bias, OT* __restrict__ C,
    int N, int nbx, int GB)
{
  constexpr int NT = KK / 32;
  static_assert(NT % 3 == 0 && NT >= 6, "KK must be multiple of 96");
  __shared__ char sm[3][20480];   // per buf: A 8KB @0, B 12KB @8192

  const int cpx = gridDim.x >> 3;
  const int xcd = blockIdx.x & 7;
  const int ci  = blockIdx.x >> 3;
  const int gsz = GB * nbx;
  const int g   = ci / gsz;
  const int r2  = ci - g * gsz;
  const int bn  = r2 / GB;
  const int bi  = r2 - bn * GB;
  const int bm  = xcd * (cpx / nbx) + g * GB + bi;
  const int m0 = bm * 128, n0 = bn * 192;

  const int tid = threadIdx.x;
  const int lane = tid & 63;
  const int wid = tid >> 6;
  const int wm = wid >> 1;
  const int wn = wid & 1;
  const int kcg = lane >> 4, rl = lane & 15;

  const __hip_bfloat16* pA[2];
  const __hip_bfloat16* pB[3];
  #pragma unroll
  for (int r = 0; r < 2; ++r) {
    const int c = tid + r * 256, row = c >> 2, slot = c & 3;
    const int kc = slot ^ ((row >> 1) & 3);
    pA[r] = A + (size_t)(m0 + row) * KK + kc * 8;
  }
  #pragma unroll
  for (int r = 0; r < 3; ++r) {
    const int c = tid + r * 256, row = c >> 2, slot = c & 3;
    const int kc = slot ^ ((row >> 1) & 3);
    pB[r] = BT + (size_t)(n0 + row) * KK + kc * 8;
  }
  auto stageT = [&](char* base, int off) {
    gld_lds16(pA[0] + off, base + tid * 16);
    gld_lds16(pA[1] + off, base + tid * 16 + 4096);
    gld_lds16(pB[0] + off, base + 8192 + tid * 16);
    gld_lds16(pB[1] + off, base + 8192 + tid * 16 + 4096);
    gld_lds16(pB[2] + off, base + 8192 + tid * 16 + 8192);
  };

  int woffA[4], woffB[6];
  #pragma unroll
  for (int m = 0; m < 4; ++m)
    woffA[m] = swz_off(wm * 64 + m * 16 + rl, kcg);
  #pragma unroll
  for (int n = 0; n < 6; ++n)
    woffB[n] = 8192 + swz_off(wn * 96 + n * 16 + rl, kcg);

  f32x4 acc[4][6] = {};
  s16x8 af[4], bf[6];
  auto reads = [&](const char* base) {
    #pragma unroll
    for (int m = 0; m < 4; ++m) af[m] = *(const s16x8*)(base + woffA[m]);
    #pragma unroll
    for (int n = 0; n < 6; ++n) bf[n] = *(const s16x8*)(base + woffB[n]);
  };
  auto mfmas = [&]() {
    #pragma unroll
    for (int m = 0; m < 4; ++m)
      #pragma unroll
      for (int n = 0; n < 6; ++n)
        acc[m][n] = __builtin_amdgcn_mfma_f32_16x16x32_bf16(af[m], bf[n], acc[m][n], 0, 0, 0);
  };

  stageT(sm[0], 0);
  stageT(sm[1], 32);
  #pragma unroll
  for (int r = 0; r < 2; ++r) pA[r] += 64;
  #pragma unroll
  for (int r = 0; r < 3; ++r) pB[r] += 64;

  #pragma unroll 1
  for (int it = 0; it < NT / 3 - 1; ++it) {
    WAITV5(); BARX(); reads(sm[0]); stageT(sm[2], 0);  mfmas();
    WAITV5(); BARX(); reads(sm[1]); stageT(sm[0], 32); mfmas();
    WAITV5(); BARX(); reads(sm[2]); stageT(sm[1], 64); mfmas();
    #pragma unroll
    for (int r = 0; r < 2; ++r) pA[r] += 96;
    #pragma unroll
    for (int r = 0; r < 3; ++r) pB[r] += 96;
  }
  WAITV5(); BARX(); reads(sm[0]); stageT(sm[2], 0); mfmas();
  WAITV5(); BARX(); reads(sm[1]); mfmas();
  WAITV0(); BARX(); reads(sm[2]); mfmas();

  const int colb = n0 + wn * 96 + rl;
  const int rowb = m0 + wm * 64 + (lane >> 4) * 4;
  float bv[6];
  #pragma unroll
  for (int n = 0; n < 6; ++n) bv[n] = BIAS ? bias[colb + n * 16] : 0.0f;
  #pragma unroll
  for (int m = 0; m < 4; ++m) {
    #pragma unroll
    for (int r = 0; r < 4; ++r) {
      const int row = rowb + m * 16 + r;
      #pragma unroll
      for (int n = 0; n < 6; ++n) {
        float v = acc[m][n][r] + bv[n];
        if (GELU) v = gelu_f(v);
        stT(C, (size_t)row * N + colb + n * 16, v);
      }
    }
  }
}

// ---------------------------------------------------------------------------
// fp32 LDS-tiled GEMM (q-projection only), templated output
// ---------------------------------------------------------------------------
template<typename OT>
__global__ __launch_bounds__(256) void gemm64(
    const float* __restrict__ A, const float* __restrict__ W,
    OT* __restrict__ C, int M, int N, int K)
{
  __shared__ float As[16][65];
  __shared__ float Ws[16][65];
  const int tid = threadIdx.x;
  const int m0 = blockIdx.y * 64;
  const int n0 = blockIdx.x * 64;
  const int tx = (tid & 15) * 4;
  const int ty = (tid >> 4) * 4;
  float acc[4][4] = {};

  for (int k0 = 0; k0 < K; k0 += 16) {
    #pragma unroll
    for (int r = 0; r < 4; ++r) {
      int idx = tid + r * 256;
      int mm = idx >> 4, kk = idx & 15;
      As[kk][mm] = A[(size_t)(m0 + mm) * K + (k0 + kk)];
    }
    #pragma unroll
    for (int r = 0; r < 4; ++r) {
      int idx = tid + r * 256;
      int kk = idx >> 6, nn = idx & 63;
      Ws[kk][nn] = W[(size_t)(k0 + kk) * N + (n0 + nn)];
    }
    __syncthreads();
    #pragma unroll
    for (int kk = 0; kk < 16; ++kk) {
      float a[4], b[4];
      #pragma unroll
      for (int i = 0; i < 4; ++i) a[i] = As[kk][ty + i];
      #pragma unroll
      for (int j = 0; j < 4; ++j) b[j] = Ws[kk][tx + j];
      #pragma unroll
      for (int i = 0; i < 4; ++i)
        #pragma unroll
        for (int j = 0; j < 4; ++j) acc[i][j] += a[i] * b[j];
    }
    __syncthreads();
  }
  #pragma unroll
  for (int i = 0; i < 4; ++i)
    #pragma unroll
    for (int j = 0; j < 4; ++j)
      stT(C, (size_t)(m0 + ty + i) * N + (n0 + tx + j), acc[i][j]);
}

// ---------------------------------------------------------------------------
// Merged weight transpose-cast: all 4 weights in ONE dispatch. (R15-proven)
// ---------------------------------------------------------------------------
__device__ __forceinline__ void tcast_body(
    const float* W, __hip_bfloat16* WT, int K, int N, int bx, int by, int tid,
    float (*t)[33])
{
  const int n0 = bx * 32, k0 = by * 32;
  const int x = tid & 31, y4 = (tid >> 5) * 4;
  #pragma unroll
  for (int i = 0; i < 4; ++i)
    t[y4 + i][x] = W[(size_t)(k0 + y4 + i) * N + n0 + x];
  __syncthreads();
  #pragma unroll
  for (int i = 0; i < 4; ++i)
    WT[(size_t)(n0 + y4 + i) * K + k0 + x] = __float2bfloat16(t[x][y4 + i]);
}

__global__ __launch_bounds__(256) void wtrans_all(
    const float* __restrict__ Wkv, __hip_bfloat16* __restrict__ WkvT,
    const float* __restrict__ Wo, __hip_bfloat16* __restrict__ WoT,
    const float* __restrict__ W1, __hip_bfloat16* __restrict__ W1T,
    const float* __restrict__ W2, __hip_bfloat16* __restrict__ W2T)
{
  __shared__ float t[32][33];
  const int bid = blockIdx.x;
  const int tid = threadIdx.x;
  if (bid < 576) {
    tcast_body(Wkv, WkvT, H_, H_, bid % 24, bid / 24, tid, t);
  } else if (bid < 1152) {
    const int s = bid - 576;
    tcast_body(Wo, WoT, H_, H_, s % 24, s / 24, tid, t);
  } else if (bid < 3456) {
    const int s = bid - 1152;
    tcast_body(W1, W1T, H_, FF_, s % 96, s / 96, tid, t);
  } else {
    const int s = bid - 3456;
    tcast_body(W2, W2T, FF_, H_, s % 24, s / 24, tid, t);
  }
}

// elementwise cast f32 -> bf16, 4 elems/thread (dedicated, zero-LDS)
__global__ __launch_bounds__(256) void cast_f32_bf16(
    const float* __restrict__ x, __hip_bfloat16* __restrict__ y, size_t n4)
{
  const size_t i = (size_t)blockIdx.x * 256 + threadIdx.x;
  if (i >= n4) return;
  const float4 v = ((const float4*)x)[i];
  __hip_bfloat16 o[4] = { __float2bfloat16(v.x), __float2bfloat16(v.y),
                          __float2bfloat16(v.z), __float2bfloat16(v.w) };
  *(ushort4*)(y + i * 4) = *(ushort4*)o;
}

// ---------------------------------------------------------------------------
// MFMA attention. Block = (s, h, b). 256 threads = 4 waves (2x2).  (R4, unchanged)
// ---------------------------------------------------------------------------
__global__ __launch_bounds__(256) void attn_mfma(
    const __hip_bfloat16* __restrict__ qp,   // [B*Q][H] bf16
    const __hip_bfloat16* __restrict__ kvp,  // [B*S*T][H] bf16
    const int* __restrict__ mask,
    __hip_bfloat16* __restrict__ res)        // [B,Q,S,H] bf16
{
  const int s = blockIdx.x, h = blockIdx.y, b = blockIdx.z;
  __shared__ __align__(16) char lds[66048];
  char* Ks = lds;
  char* VT = lds + 16384;
  char* SC = lds + 32768;
  float* mv = (float*)(lds + 65536);

  const int tid = threadIdx.x;
  const int lane = tid & 63;
  const int wid = tid >> 6;
  const int wr = wid >> 1, wc = wid & 1;
  const int kcg = lane >> 4, rl = lane & 15;

  if (tid < 128) mv[tid] = (float)mask[((size_t)b * S_ + s) * T_ + tid] * -10000.0f;

  {
    const __hip_bfloat16* qb = qp + ((size_t)b * Q_) * H_ + h * HD_;
    #pragma unroll
    for (int r = 0; r < 2; ++r) {
      const int c = tid + r * 256;
      const int qq = c >> 3, sc = c & 7;
      const int kc8 = sc ^ (qq & 7);
      gld_lds16(qb + (size_t)qq * H_ + kc8 * 8, SC + c * 16);
    }
  }
  {
    const int kc8 = tid & 7, tg = tid >> 3;
    const int t0 = tg * 4;
    const __hip_bfloat16* kb = kvp + (((size_t)b * S_ + s) * T_) * H_ + h * HD_ + kc8 * 8;
    s16x8 r0 = *(const s16x8*)(kb + (size_t)(t0 + 0) * H_);
    s16x8 r1 = *(const s16x8*)(kb + (size_t)(t0 + 1) * H_);
    s16x8 r2 = *(const s16x8*)(kb + (size_t)(t0 + 2) * H_);
    s16x8 r3 = *(const s16x8*)(kb + (size_t)(t0 + 3) * H_);
    *(s16x8*)(Ks + (t0 + 0) * 128 + ((kc8 ^ ((t0 + 0) & 7)) << 4)) = r0;
    *(s16x8*)(Ks + (t0 + 1) * 128 + ((kc8 ^ ((t0 + 1) & 7)) << 4)) = r1;
    *(s16x8*)(Ks + (t0 + 2) * 128 + ((kc8 ^ ((t0 + 2) & 7)) << 4)) = r2;
    *(s16x8*)(Ks + (t0 + 3) * 128 + ((kc8 ^ ((t0 + 3) & 7)) << 4)) = r3;
    const int tc = tg >> 1;
    const int toff = (tg & 1) * 8;
    #pragma unroll
    for (int j = 0; j < 8; ++j) {
      s16x4 v4 = { r0[j], r1[j], r2[j], r3[j] };
      const int d = kc8 * 8 + j;
      *(s16x4*)(VT + d * 256 + ((tc ^ (d & 15)) << 4) + toff) = v4;
    }
  }
  __syncthreads();

  f32x4 acc[2][4] = {};
  {
    s16x8 af[2][2], bf[2][4];
    #pragma unroll
    for (int kk = 0; kk < 2; ++kk) {
      #pragma unroll
      for (int m = 0; m < 2; ++m) {
        const int q = wr * 32 + m * 16 + rl;
        const int kc8 = kk * 4 + kcg;
        af[kk][m] = *(const s16x8*)(SC + q * 128 + ((kc8 ^ (q & 7)) << 4));
      }
      #pragma unroll
      for (int n = 0; n < 4; ++n) {
        const int t = wc * 64 + n * 16 + rl;
        const int kc8 = kk * 4 + kcg;
        bf[kk][n] = *(const s16x8*)(Ks + t * 128 + ((kc8 ^ (t & 7)) << 4));
      }
    }
    #pragma unroll
    for (int kk = 0; kk < 2; ++kk)
      #pragma unroll
      for (int m = 0; m < 2; ++m)
        #pragma unroll
        for (int n = 0; n < 4; ++n)
          acc[m][n] = __builtin_amdgcn_mfma_f32_16x16x32_bf16(af[kk][m], bf[kk][n], acc[m][n], 0, 0, 0);
  }
  __syncthreads();

  #pragma unroll
  for (int m = 0; m < 2; ++m)
    #pragma unroll
    for (int n = 0; n < 4; ++n)
      #pragma unroll
      for (int r = 0; r < 4; ++r) {
        const int q = wr * 32 + m * 16 + (lane >> 4) * 4 + r;
        const int t = wc * 64 + n * 16 + rl;
        const int tc32 = t >> 2;
        *(float*)(SC + q * 512 + ((tc32 ^ (q & 31)) << 4) + (t & 3) * 4) =
            acc[m][n][r] * 0.125f + mv[t];
      }
  __syncthreads();

  {
    const int q = tid >> 2, quarter = tid & 3;
    float vals[32];
    #pragma unroll
    for (int j = 0; j < 8; ++j) {
      const int tc32 = quarter * 8 + j;
      const f32x4 c = *(const f32x4*)(SC + q * 512 + ((tc32 ^ (q & 31)) << 4));
      vals[j * 4 + 0] = c[0]; vals[j * 4 + 1] = c[1];
      vals[j * 4 + 2] = c[2]; vals[j * 4 + 3] = c[3];
    }
    float mx = -1e30f;
    #pragma unroll
    for (int i = 0; i < 32; ++i) mx = fmaxf(mx, vals[i]);
    mx = fmaxf(mx, __shfl_xor(mx, 1, 64));
    mx = fmaxf(mx, __shfl_xor(mx, 2, 64));
    float sum = 0.0f;
    #pragma unroll
    for (int i = 0; i < 32; ++i) { vals[i] = expf(vals[i] - mx); sum += vals[i]; }
    sum += __shfl_xor(sum, 1, 64);
    sum += __shfl_xor(sum, 2, 64);
    const float inv = 1.0f / sum;
    #pragma unroll
    for (int jj = 0; jj < 4; ++jj) {
      const int tcp = quarter * 4 + jj;
      s16x8 pk;
      #pragma unroll
      for (int i = 0; i < 8; ++i) pk[i] = f2bf(vals[jj * 8 + i] * inv);
      *(s16x8*)(SC + q * 512 + ((tcp ^ (q & 15)) << 4)) = pk;
    }
  }
  __syncthreads();

  f32x4 oacc[2][2] = {};
  #pragma unroll
  for (int kt = 0; kt < 4; ++kt) {
    s16x8 pa[2], vb[2];
    #pragma unroll
    for (int m = 0; m < 2; ++m) {
      const int q = wr * 32 + m * 16 + rl;
      const int tcp = kt * 4 + kcg;
      pa[m] = *(const s16x8*)(SC + q * 512 + ((tcp ^ (q & 15)) << 4));
    }
    #pragma unroll
    for (int n = 0; n < 2; ++n) {
      const int d = wc * 32 + n * 16 + rl;
      const int tc = kt * 4 + kcg;
      vb[n] = *(const s16x8*)(VT + d * 256 + ((tc ^ (d & 15)) << 4));
    }
    #pragma unroll
    for (int m = 0; m < 2; ++m)
      #pragma unroll
      for (int n = 0; n < 2; ++n)
        oacc[m][n] = __builtin_amdgcn_mfma_f32_16x16x32_bf16(pa[m], vb[n], oacc[m][n], 0, 0, 0);
  }
  #pragma unroll
  for (int m = 0; m < 2; ++m)
    #pragma unroll
    for (int n = 0; n < 2; ++n)
      #pragma unroll
      for (int r = 0; r < 4; ++r) {
        const int q = wr * 32 + m * 16 + (lane >> 4) * 4 + r;
        const int d = wc * 32 + n * 16 + rl;
        res[(((size_t)b * Q_ + q) * S_ + s) * H_ + h * HD_ + d] =
            __float2bfloat16(oacc[m][n][r]);
      }
}

// ---------------------------------------------------------------------------
// Wave-per-row LayerNorm over H=768: 4 waves/block = 4 rows/block.
// 12 elems/lane (stride-64, coalesced), butterfly shfl_xor reduce, no LDS.
// ---------------------------------------------------------------------------
template<bool ADD, typename IT, typename OT>
__global__ __launch_bounds__(256) void ln_kernel(
    const IT* __restrict__ X, const IT* __restrict__ X2,
    const float* __restrict__ g, const float* __restrict__ bta,
    OT* __restrict__ Y)
{
  const int wv = threadIdx.x >> 6;
  const int lane = threadIdx.x & 63;
  const size_t row = (size_t)blockIdx.x * 4 + wv;
  float v[12];
  #pragma unroll
  for (int i = 0; i < 12; ++i) {
    const int c = lane + i * 64;
    v[i] = ldT(X, row * H_ + c);
    if (ADD) v[i] += ldT(X2, row * H_ + c);
  }
  float sum = 0.0f;
  #pragma unroll
  for (int i = 0; i < 12; ++i) sum += v[i];
  #pragma unroll
  for (int off = 32; off > 0; off >>= 1) sum += __shfl_xor(sum, off, 64);
  const float mean = sum * (1.0f / 768.0f);
  float vs = 0.0f;
  #pragma unroll
  for (int i = 0; i < 12; ++i) { v[i] -= mean; vs += v[i] * v[i]; }
  #pragma unroll
  for (int off = 32; off > 0; off >>= 1) vs += __shfl_xor(vs, off, 64);
  const float rstd = rsqrtf(vs * (1.0f / 768.0f) + 1e-12f);
  #pragma unroll
  for (int i = 0; i < 12; ++i) {
    const int c = lane + i * 64;
    stT(Y, row * H_ + c, v[i] * rstd * g[c] + bta[c]);
  }
}

// ---------------------------------------------------------------------------
extern "C" void kernel_launch(void* const* d_in, const int* in_sizes, int n_in,
                              void* d_out, int out_size, void* d_ws, size_t ws_size,
                              hipStream_t stream) {
  const float* q    = (const float*)d_in[0];
  const float* k    = (const float*)d_in[1];
  const int*   mask = (const int*)d_in[2];
  const float* Wq   = (const float*)d_in[3];
  const float* Wkv  = (const float*)d_in[4];
  const float* Wo   = (const float*)d_in[5];
  const float* bo   = (const float*)d_in[6];
  const float* ln1g = (const float*)d_in[7];
  const float* ln1b = (const float*)d_in[8];
  const float* W1   = (const float*)d_in[9];
  const float* b1   = (const float*)d_in[10];
  const float* W2   = (const float*)d_in[11];
  const float* b2   = (const float*)d_in[12];
  const float* ln2g = (const float*)d_in[13];
  const float* ln2b = (const float*)d_in[14];
  float* out = (float*)d_out;

  const int MROWS = B_ * Q_ * S_;           // 24576
  const int KVROWS = B_ * S_ * T_;          // 49152

  // workspace layout (bytes), lifetime-based reuse:
  char* ws = (char*)d_ws;
  __hip_bfloat16* kbf  = (__hip_bfloat16*)ws;                        // 75.5MB [dead after kv gemm]
  __hip_bfloat16* apre = (__hip_bfloat16*)ws;                        // 37.7MB (reuses kbf; dead after LN1)
  __hip_bfloat16* kvp  = (__hip_bfloat16*)(ws + 75497472);           // 75.5MB [dead after attn]
  __hip_bfloat16* ffn1 = (__hip_bfloat16*)ws;                        // 151MB (reuses kbf/apre+kvp)
  __hip_bfloat16* ares = (__hip_bfloat16*)(ws + 150994944);          // 37.7MB [dead after Wo gemm]
  __hip_bfloat16* ffn2 = ares;                                       // reuse
  __hip_bfloat16* aln  = (__hip_bfloat16*)(ws + 188743680);          // 37.7MB
  __hip_bfloat16* qp   = (__hip_bfloat16*)(ws + 226492416);          // 0.8MB (bf16)
  __hip_bfloat16* WkvT = (__hip_bfloat16*)(ws + 228065280);
  __hip_bfloat16* WoT  = (__hip_bfloat16*)(ws + 229244928);
  __hip_bfloat16* W1T  = (__hip_bfloat16*)(ws + 230424576);
  __hip_bfloat16* W2T  = (__hip_bfloat16*)(ws + 235143168);

  dim3 blk(256);

  // weight prep: big cast first, merged transposes, q-proj
  cast_f32_bf16<<<dim3((KVROWS * H_ / 4 + 255) / 256), blk, 0, stream>>>(
      k, kbf, (size_t)KVROWS * H_ / 4);
  wtrans_all<<<dim3(5760), blk, 0, stream>>>(
      Wkv, WkvT, Wo, WoT, W1, W1T, W2, W2T);

  // 1. q projection (fp32 in, bf16 out)
  gemm64<__hip_bfloat16><<<dim3(H_ / 64, 512 / 64), blk, 0, stream>>>(
      q, Wq, qp, 512, H_, H_);
  // 2. kv projection -> bf16  [FAT 128x192]  grid 384*4=1536, cpx=192,
  //    nbx=4, GB=6 (gsz=24 | 192); exactly 3 full rounds at 2 blocks/CU
  gemm_fat<768, __hip_bfloat16, false, false>
      <<<dim3((KVROWS / 128) * (H_ / 192)), blk, 0, stream>>>(
      kbf, WkvT, nullptr, kvp, H_, H_ / 192, 6);
  // 3. MFMA attention -> ares (bf16)
  attn_mfma<<<dim3(S_, NH_, B_), blk, 0, stream>>>(qp, kvp, mask, ares);
  // 4. ares @ Wo + bo -> apre (bf16)   grid 192*6=1152, cpx=144, GB=6
  gemm_mfma<768, __hip_bfloat16, true, false>
      <<<dim3((MROWS / 128) * (H_ / 128)), blk, 0, stream>>>(
      ares, WoT, bo, apre, H_, H_ / 128, 6);
  // 5. LN1: apre -> aln (bf16)   [wave-per-row, grid 6144]
  ln_kernel<false, __hip_bfloat16, __hip_bfloat16><<<MROWS / 4, blk, 0, stream>>>(
      apre, nullptr, ln1g, ln1b, aln);
  // 6. aln @ W1 + b1, gelu -> ffn1 (bf16)  [FAT 128x192]
  //    grid 192*16=3072, cpx=384, nbx=16, GB=6 (gsz=96 | 384)
  gemm_fat<768, __hip_bfloat16, true, true>
      <<<dim3((MROWS / 128) * (FF_ / 192)), blk, 0, stream>>>(
      aln, W1T, b1, ffn1, FF_, FF_ / 192, 6);
  // 7. ffn1 @ W2 + b2 -> ffn2 (bf16)  [FAT 128x192]
  //    grid 192*4=768, cpx=96, nbx=4, GB=6 (gsz=24 | 96), K=3072
  gemm_fat<3072, __hip_bfloat16, true, false>
      <<<dim3((MROWS / 128) * (H_ / 192)), blk, 0, stream>>>(
      ffn1, W2T, b2, ffn2, H_, H_ / 192, 6);
  // 8. LN2: out = LN(aln + ffn2)   [wave-per-row, grid 6144]
  ln_kernel<true, __hip_bfloat16, float><<<MROWS / 4, blk, 0, stream>>>(
      aln, ffn2, ln2g, ln2b, out);
}